// Round 3
// baseline (920.518 us; speedup 1.0000x reference)
//
#include <hip/hip_runtime.h>
#include <hip/hip_cooperative_groups.h>
#include <cstdint>
#include <cstddef>

namespace cg = cooperative_groups;

#define B 32
#define H 12
#define L 512
#define D 768
#define KSEL 255
#define GN 256   // blocks (1 per CU)
#define NT 768   // threads per block (12 waves)

// workspace byte offsets; [0, OFF_CB) zeroed in-kernel at P0 (imp+sent+y contiguous)
#define OFF_IMP   0          // float[B*L]      65536
#define OFF_SENT  65536      // float[B*D]      98304
#define OFF_Y     163840     // float[B*H*D]  1179648
#define ZERO_F4   83968      // float4 count of [0,1343488)
#define OFF_CB    1343488    // float[B*H]       1536
#define OFF_A     1345024    // float[B*H*D]  1179648
#define OFF_LG    2524672    // float[B*H*L]   786432
#define OFF_SEL   3311104    // int[B*KSEL]     32640

union ShMem {
  struct { float4 red[768]; } imp;                                          // 12 KB
  struct { float4 red2[12][192]; float r1[8]; float r2[8]; float a[64]; } sent; // ~37 KB
  struct { float qpart[12][64]; float q_s[64]; } qa;                        // 3.3 KB
  struct { float v[512]; int sc[512]; } prep;                               // 4 KB
  struct { float wl[H * L]; float Ms[H]; float Is[H]; float wn[NT]; } ys;   // ~28 KB
  struct { float c[D]; } ctxout;                                            // 3 KB
};

// ---- imp tile (b,h): full 512x512, 6 row-groups x 128 lanes (float4 cols) ----
__device__ __forceinline__ void imp_vb(const float* __restrict__ sas,
                                       const float* __restrict__ am,
                                       float* __restrict__ imp,
                                       int vb, int t, float4* red) {
  const int b = vb / H, h = vb % H;
  const int g = t >> 7, c = t & 127;
  const float* base = sas + ((size_t)(b * H + h)) * L * L;
  const float* amb = am + b * L;
  float a0 = 0.f, a1 = 0.f, a2 = 0.f, a3 = 0.f;
#pragma unroll 4
  for (int l = g; l < L; l += 6) {
    const float m = (amb[l] > -10.0f) ? 1.0f : 0.0f;
    const float4 v = reinterpret_cast<const float4*>(base + (size_t)l * L)[c];
    a0 += m * v.x;
    a1 += m * v.y;
    a2 += m * v.z;
    a3 += m * v.w;
  }
  red[t] = make_float4(a0, a1, a2, a3);
  __syncthreads();
  if (g == 0) {
    float4 s = red[c];
#pragma unroll
    for (int gg = 1; gg < 6; ++gg) {
      const float4 u = red[gg * 128 + c];
      s.x += u.x; s.y += u.y; s.z += u.z; s.w += u.w;
    }
    float* ip = imp + b * L + c * 4;
    atomicAdd(ip + 0, s.x);
    atomicAdd(ip + 1, s.y);
    atomicAdd(ip + 2, s.z);
    atomicAdd(ip + 3, s.w);
  }
  __syncthreads();
}

// ---- sent unit (b, c-chunk of 64 rows): inline softmax(am) then weighted row-sum ----
__device__ __forceinline__ void sent_unit(const float* __restrict__ am,
                                          const float* __restrict__ hs,
                                          float* __restrict__ sent,
                                          int u, int t, ShMem& sh) {
  const int b = u >> 3, c = u & 7;
  const int w = t >> 6, lane = t & 63;
  const float aml = (t < L) ? am[b * L + t] : -INFINITY;
  float m = aml;
#pragma unroll
  for (int o = 32; o; o >>= 1) m = fmaxf(m, __shfl_down(m, o));
  if (t < L && lane == 0) sh.sent.r1[w] = m;
  __syncthreads();
  if (t == 0) {
    float mm = sh.sent.r1[0];
    for (int i = 1; i < 8; ++i) mm = fmaxf(mm, sh.sent.r1[i]);
    sh.sent.r1[0] = mm;
  }
  __syncthreads();
  const float M = sh.sent.r1[0];
  const float e = (t < L) ? expf(aml - M) : 0.f;
  float s = e;
#pragma unroll
  for (int o = 32; o; o >>= 1) s += __shfl_down(s, o);
  if (t < L && lane == 0) sh.sent.r2[w] = s;
  __syncthreads();
  if (t == 0) {
    float ss = 0.f;
    for (int i = 0; i < 8; ++i) ss += sh.sent.r2[i];
    sh.sent.r2[0] = ss;
  }
  __syncthreads();
  const float S = sh.sent.r2[0];
  if (t >= c * 64 && t < c * 64 + 64) sh.sent.a[t - c * 64] = e / S;
  __syncthreads();
  const float* h0 = hs + ((size_t)b * L + c * 64) * D;
  float4 s0 = {0, 0, 0, 0}, s1 = {0, 0, 0, 0}, s2 = {0, 0, 0, 0};
  for (int l = w; l < 64; l += 12) {
    const float al = sh.sent.a[l];
    const float4* row = reinterpret_cast<const float4*>(h0 + (size_t)l * D);
    const float4 v0 = row[lane], v1 = row[lane + 64], v2 = row[lane + 128];
    s0.x += al * v0.x; s0.y += al * v0.y; s0.z += al * v0.z; s0.w += al * v0.w;
    s1.x += al * v1.x; s1.y += al * v1.y; s1.z += al * v1.z; s1.w += al * v1.w;
    s2.x += al * v2.x; s2.y += al * v2.y; s2.z += al * v2.z; s2.w += al * v2.w;
  }
  sh.sent.red2[w][lane] = s0;
  sh.sent.red2[w][lane + 64] = s1;
  sh.sent.red2[w][lane + 128] = s2;
  __syncthreads();
  if (t < 192) {
    float4 acc = {0, 0, 0, 0};
#pragma unroll
    for (int ww = 0; ww < 12; ++ww) {
      const float4 uu = sh.sent.red2[ww][t];
      acc.x += uu.x; acc.y += uu.y; acc.z += uu.z; acc.w += uu.w;
    }
    float* sp = sent + b * D + t * 4;
    atomicAdd(sp + 0, acc.x);
    atomicAdd(sp + 1, acc.y);
    atomicAdd(sp + 2, acc.z);
    atomicAdd(sp + 3, acc.w);
  }
  __syncthreads();
}

// ---- fused q -> cb -> A per (b,h); q never materialized ----
__device__ __forceinline__ void qa_unit(const float* __restrict__ sent,
                                        const float* __restrict__ Wq,
                                        const float* __restrict__ bq,
                                        const float* __restrict__ bk,
                                        const float* __restrict__ Wk,
                                        float* __restrict__ cbg,
                                        float* __restrict__ Ag,
                                        int u, int t, ShMem& sh) {
  const int b = u / H, h = u % H;
  const int w = t >> 6, lane = t & 63;
  const float* sb = sent + b * D;
  const float* wq = Wq + (size_t)(w * 64) * D + h * 64 + lane;
  float acc = 0.f;
#pragma unroll 8
  for (int dd = 0; dd < 64; ++dd) acc += sb[w * 64 + dd] * wq[(size_t)dd * D];
  sh.qa.qpart[w][lane] = acc;
  __syncthreads();
  if (t < 64) {
    float q = bq[h * 64 + t];
#pragma unroll
    for (int ww = 0; ww < 12; ++ww) q += sh.qa.qpart[ww][t];
    sh.qa.q_s[t] = q;
  }
  __syncthreads();
  if (t < 64) {
    float v = bk[h * 64 + t] * sh.qa.q_s[t];
#pragma unroll
    for (int o = 32; o; o >>= 1) v += __shfl_down(v, o);
    if (t == 0) cbg[b * H + h] = v;
  }
  // A[b,h,d] for d = t
  const float4* wkrow = reinterpret_cast<const float4*>(Wk + (size_t)t * D + h * 64);
  float a0 = 0.f, a1 = 0.f, a2 = 0.f, a3 = 0.f;
#pragma unroll
  for (int cc = 0; cc < 16; ++cc) {
    const float4 wv = wkrow[cc];
    a0 += wv.x * sh.qa.q_s[cc * 4 + 0];
    a1 += wv.y * sh.qa.q_s[cc * 4 + 1];
    a2 += wv.z * sh.qa.q_s[cc * 4 + 2];
    a3 += wv.w * sh.qa.q_s[cc * 4 + 3];
  }
  Ag[((size_t)b * H + h) * D + t] = (a0 + a1) + (a2 + a3);
  __syncthreads();
}

__global__ __launch_bounds__(NT, 3) void k_mega(
    const float* __restrict__ hs, const float* __restrict__ am,
    const float* __restrict__ sas,
    const float* __restrict__ Wq, const float* __restrict__ bq,
    const float* __restrict__ Wk, const float* __restrict__ bk,
    const float* __restrict__ Wv, const float* __restrict__ bv,
    const float* __restrict__ Wo, const float* __restrict__ bo,
    float* __restrict__ imp, float* __restrict__ sent, float* __restrict__ y,
    float* __restrict__ cbg, float* __restrict__ Ag, float* __restrict__ lg,
    int* __restrict__ sel, float* __restrict__ out_tok,
    float* __restrict__ out_mask, float* __restrict__ out_tome) {
  cg::grid_group grid = cg::this_grid();
  __shared__ ShMem sh;
  const int bid = blockIdx.x, t = threadIdx.x;

  // ---- P0: zero imp+sent+y; tome ones; mask tail ----
  {
    const int gtid = bid * NT + t;
    float4* zz = reinterpret_cast<float4*>(imp);  // imp/sent/y contiguous
    if (gtid < ZERO_F4) zz[gtid] = make_float4(0.f, 0.f, 0.f, 0.f);
    if (gtid < B * 256) out_tome[gtid] = 1.0f;
    if (gtid < B) out_mask[gtid * 256 + 255] = 0.0f;
  }
  grid.sync();

  // ---- P1: imp tiles 0..191 || sent (inline att) ----
  if (bid < 192) {
    imp_vb(sas, am, imp, bid, t, sh.imp.red);
  } else {
    for (int k = 0; k < 4; ++k) sent_unit(am, hs, sent, (bid - 192) + 64 * k, t, sh);
  }
  grid.sync();

  // ---- P2: imp tiles 192..383 || fused q/cb/A ----
  if (bid >= 64) {
    imp_vb(sas, am, imp, 192 + (bid - 64), t, sh.imp.red);
  } else {
    for (int k = 0; k < 6; ++k) qa_unit(sent, Wq, bq, bk, Wk, cbg, Ag, bid + 64 * k, t, sh);
  }
  grid.sync();

  // ---- P3: top-255 select (blocks 0..31) || logits (blocks 32..255) ----
  if (bid < B) {
    const int b = bid;
    float aml = 0.f, val = 0.f;
    if (t < L) {
      aml = am[b * L + t];
      val = (t == 0) ? INFINITY : ((aml > -10.0f) ? imp[b * L + t] : 0.0f);
      sh.prep.v[t] = val;
    }
    __syncthreads();
    int r = 0;
    if (t < L) {
      for (int tt = 0; tt < L; ++tt) {
        const float vt = sh.prep.v[tt];
        r += (vt > val) || (vt == val && tt < t);
      }
      sh.prep.sc[t] = (r < KSEL) ? 1 : 0;
    }
    const int f = (t < L) && (r < KSEL);
    __syncthreads();
    for (int off = 1; off < L; off <<= 1) {
      int add = 0;
      if (t < L && t >= off) add = sh.prep.sc[t - off];
      __syncthreads();
      if (t < L) sh.prep.sc[t] += add;
      __syncthreads();
    }
    if (f) {
      const int pos = sh.prep.sc[t] - 1;  // 0..254
      sel[b * KSEL + pos] = t;
      out_mask[b * 256 + pos] = aml;
    }
  } else {
    const int h = t >> 6, lane = t & 63;
    for (int u = bid - 32; u < B * 16; u += 224) {
      const int b = u >> 4, ch = u & 15;
      const float cbh = cbg[b * H + h];
      float Areg[12];
#pragma unroll
      for (int k = 0; k < 12; ++k) Areg[k] = Ag[((size_t)b * H + h) * D + lane + 64 * k];
      const float* h0 = hs + (size_t)b * L * D;
      for (int li = 0; li < 32; ++li) {
        const int l = ch * 32 + li;
        const float* xr = h0 + (size_t)l * D;
        float a = 0.f;
#pragma unroll
        for (int k = 0; k < 12; ++k) a += xr[lane + 64 * k] * Areg[k];
#pragma unroll
        for (int o = 32; o; o >>= 1) a += __shfl_down(a, o);
        if (lane == 0) lg[((size_t)b * H + h) * L + l] = (a + cbh) * 0.125f;
      }
    }
  }
  grid.sync();

  // ---- P4: ysoft (all 256 blocks) then gather ----
  {
    const int b = bid >> 3, c = bid & 7;
    for (int i = t; i < H * L; i += NT) {
      const int l = i & (L - 1);
      const float aml = am[b * L + l];
      sh.ys.wl[i] = (aml < -10.0f) ? -INFINITY : lg[(size_t)b * H * L + i];
    }
    __syncthreads();
    {
      const int h = t >> 6, lane = t & 63;
      float m = -INFINITY;
#pragma unroll
      for (int k = 0; k < 8; ++k) m = fmaxf(m, sh.ys.wl[h * L + lane + 64 * k]);
#pragma unroll
      for (int o = 32; o; o >>= 1) m = fmaxf(m, __shfl_xor(m, o));
      float s = 0.f;
#pragma unroll
      for (int k = 0; k < 8; ++k) s += expf(sh.ys.wl[h * L + lane + 64 * k] - m);
#pragma unroll
      for (int o = 32; o; o >>= 1) s += __shfl_xor(s, o);
      if (lane == 0) { sh.ys.Ms[h] = m; sh.ys.Is[h] = 1.0f / s; }
    }
    __syncthreads();
    {
      const int h = t >> 6, l = t & 63;
      sh.ys.wn[t] = expf(sh.ys.wl[h * L + c * 64 + l] - sh.ys.Ms[h]) * sh.ys.Is[h];
    }
    __syncthreads();
    const float* h0 = hs + ((size_t)b * L + c * 64) * D;
    float acc[12];
#pragma unroll
    for (int h = 0; h < 12; ++h) acc[h] = 0.f;
    for (int l = 0; l < 64; ++l) {
      const float x = h0[(size_t)l * D + t];
#pragma unroll
      for (int h = 0; h < 12; ++h) acc[h] += sh.ys.wn[h * 64 + l] * x;
    }
#pragma unroll
    for (int h = 0; h < 12; ++h) atomicAdd(&y[((size_t)b * H + h) * D + t], acc[h]);
  }
  {  // gather preserved rows
    const int w = t >> 6, lane = t & 63;
    for (int rr = bid * 12 + w; rr < B * KSEL; rr += GN * 12) {
      const int b2 = rr / KSEL, p = rr % KSEL;
      const int j = sel[rr];
      const float4* src = reinterpret_cast<const float4*>(hs + ((size_t)b2 * L + j) * D);
      float4* dst = reinterpret_cast<float4*>(out_tok + ((size_t)b2 * 256 + p) * D);
#pragma unroll
      for (int i = 0; i < 3; ++i) dst[lane + 64 * i] = src[lane + 64 * i];
    }
  }
  grid.sync();

  // ---- P5: ctx -> LDS -> new_token (blocks 0..31, one b each) ----
  if (bid < B) {
    const int b = bid;
    const float* yh = y + ((size_t)b * H + (t >> 6)) * D;
    float a0 = 0.f, a1 = 0.f, a2 = 0.f, a3 = 0.f;
#pragma unroll 4
    for (int d = 0; d < D; d += 4) {
      a0 += yh[d + 0] * Wv[(size_t)(d + 0) * D + t];
      a1 += yh[d + 1] * Wv[(size_t)(d + 1) * D + t];
      a2 += yh[d + 2] * Wv[(size_t)(d + 2) * D + t];
      a3 += yh[d + 3] * Wv[(size_t)(d + 3) * D + t];
    }
    sh.ctxout.c[t] = bv[t] + ((a0 + a1) + (a2 + a3));
    __syncthreads();
    float b0 = 0.f, b1 = 0.f, b2 = 0.f, b3 = 0.f;
#pragma unroll 4
    for (int u2 = 0; u2 < D; u2 += 4) {
      b0 += sh.ctxout.c[u2 + 0] * Wo[(size_t)(u2 + 0) * D + t];
      b1 += sh.ctxout.c[u2 + 1] * Wo[(size_t)(u2 + 1) * D + t];
      b2 += sh.ctxout.c[u2 + 2] * Wo[(size_t)(u2 + 2) * D + t];
      b3 += sh.ctxout.c[u2 + 3] * Wo[(size_t)(u2 + 3) * D + t];
    }
    out_tok[((size_t)b * 256 + 255) * D + t] = bo[t] + ((b0 + b1) + (b2 + b3));
  }
}

extern "C" void kernel_launch(void* const* d_in, const int* in_sizes, int n_in,
                              void* d_out, int out_size, void* d_ws, size_t ws_size,
                              hipStream_t stream) {
  const float* hs = (const float*)d_in[0];
  const float* am = (const float*)d_in[1];
  const float* sas = (const float*)d_in[2];
  const float* Wq = (const float*)d_in[3];
  const float* bq = (const float*)d_in[4];
  const float* Wk = (const float*)d_in[5];
  const float* bk = (const float*)d_in[6];
  const float* Wv = (const float*)d_in[7];
  const float* bv = (const float*)d_in[8];
  const float* Wo = (const float*)d_in[9];
  const float* bo = (const float*)d_in[10];

  float* out_tok = (float*)d_out;                   // [B,256,D]
  float* out_mask = out_tok + (size_t)B * 256 * D;  // [B,1,1,256]
  float* out_tome = out_mask + (size_t)B * 256;     // [B,256,1]

  char* ws = (char*)d_ws;
  float* imp = (float*)(ws + OFF_IMP);
  float* sent = (float*)(ws + OFF_SENT);
  float* yg = (float*)(ws + OFF_Y);
  float* cbg = (float*)(ws + OFF_CB);
  float* Ag = (float*)(ws + OFF_A);
  float* lg = (float*)(ws + OFF_LG);
  int* sel = (int*)(ws + OFF_SEL);

  void* args[] = {(void*)&hs, (void*)&am, (void*)&sas, (void*)&Wq, (void*)&bq,
                  (void*)&Wk, (void*)&bk, (void*)&Wv, (void*)&bv, (void*)&Wo,
                  (void*)&bo, (void*)&imp, (void*)&sent, (void*)&yg, (void*)&cbg,
                  (void*)&Ag, (void*)&lg, (void*)&sel, (void*)&out_tok,
                  (void*)&out_mask, (void*)&out_tome};
  hipLaunchCooperativeKernel((void*)k_mega, dim3(GN), dim3(NT), args, 0, stream);
}